// Round 7
// baseline (730.412 us; speedup 1.0000x reference)
//
#include <hip/hip_runtime.h>

typedef __bf16 bf16x8 __attribute__((ext_vector_type(8)));
typedef float  f32x4  __attribute__((ext_vector_type(4)));
typedef float  f32x2  __attribute__((ext_vector_type(2)));
typedef unsigned int u32x4 __attribute__((ext_vector_type(4)));
typedef unsigned short u16;

#define NPTS 8192
#define NB   4
#define KNN  16
#define ROW  136        // u16 per row; 272 B = 17 x 16B
#define CF   131
#define JBLK 136
#define NSTEP 34        // K = 1088 = 34*32
#define AGG_STRIDE 1096 // u16 (2192 B per point)
#define HALF_U16 8704   // 64 rows * 136 u16 per ping-pong half
#define WOFF  17408     // u16 idx: w bf16 [16p][16k][8j]
#define RBOFF 19456     // u16 idx: rb table (u16[256])
#define SMEM_U16 19712  // 39424 B total
// mode-1 tail aliases (all inside dead rowbuf/agg region)
#define F2T   0         // u16[16][128]
#define H1OFF 2304      // u16, stride 136
#define FFOFF 4608      // u16 idx -> float* (byte 9216), stride 68 floats
#define NEG 0.1f

#define WAITVM(n) __builtin_amdgcn_s_waitcnt(0x0F70 | (n))
#define SB() __builtin_amdgcn_sched_barrier(0)

__device__ __forceinline__ float b2f(u16 h) {
    return __uint_as_float(((unsigned int)h) << 16);
}
__device__ __forceinline__ u16 f2bf(float f) {
    unsigned int u = __float_as_uint(f);
    unsigned int r = (u + 0x7FFFu + ((u >> 16) & 1u)) >> 16;
    return (u16)r;
}
__device__ __forceinline__ void dma16(const u16* g, u16* l) {
    __builtin_amdgcn_global_load_lds(
        (const __attribute__((address_space(1))) void*)g,
        (__attribute__((address_space(3))) void*)l, 16, 0, 0);
}
__device__ __forceinline__ float lrelu(float v) {
    return (v < 0.0f) ? NEG * v : v;
}

// ---------------------------------------------------------------------------
__global__ __launch_bounds__(256) void pack_fcT(
    const float* __restrict__ xyz, const float* __restrict__ feat,
    u16* __restrict__ fcT1, u16* __restrict__ fcT2, float* __restrict__ xyzF)
{
    __shared__ u16 tile[CF * 65];
    int t = threadIdx.x;
    int blk = blockIdx.x;
    int b = blk >> 7;
    int n0 = (blk & 127) << 6;
    int nn = t & 63;
    for (int c = (t >> 6); c < CF; c += 4) {
        float v;
        if (c < 3) v = xyz[(size_t)b * 3 * NPTS + (size_t)c * NPTS + n0 + nn];
        else       v = feat[(size_t)b * 128 * NPTS + (size_t)(c - 3) * NPTS + n0 + nn];
        tile[c * 65 + nn] = f2bf(v);
        if (c < 3) xyzF[((size_t)b * NPTS + n0 + nn) * 4 + c] = v;
    }
    __syncthreads();
    for (int e = t; e < 64 * ROW; e += 256) {
        int r = e / ROW;
        int c = e - r * ROW;
        u16 v = (c < CF) ? tile[c * 65 + r] : (u16)0;
        size_t row = (size_t)b * NPTS + n0 + r;
        fcT1[row * ROW + c] = v;
        if (c < 3 || c >= CF) fcT2[row * ROW + c] = v;
    }
}

// ---------------------------------------------------------------------------
// All four weight packs in one launch. Segments: [0,68) lw1, [68,136) lw2,
// [136,144) m1, [144,148) m2.
__global__ __launch_bounds__(256) void pack_wall(
    const float* __restrict__ l1, const float* __restrict__ l2,
    const float* __restrict__ w1, const float* __restrict__ w2,
    u16* __restrict__ o1, u16* __restrict__ o2,
    u16* __restrict__ o3, u16* __restrict__ o4)
{
    int blk = blockIdx.x;
    const float* w; u16* out; int O, Cin, remap, b0;
    if (blk < 68)       { w = l1; out = o1; O = 128; Cin = 1048; remap = 1; b0 = 0; }
    else if (blk < 136) { w = l2; out = o2; O = 128; Cin = 1048; remap = 1; b0 = 68; }
    else if (blk < 144) { w = w1; out = o3; O = 128; Cin = 128;  remap = 0; b0 = 136; }
    else                { w = w2; out = o4; O = 64;  Cin = 128;  remap = 0; b0 = 144; }
    int T = O >> 4;
    int tid = (blk - b0) * 256 + threadIdx.x;
    int l = tid & 63;
    int st = tid >> 6;
    int tt = st % T;
    int s = st / T;
    int o = tt * 16 + (l & 15);
    int kb = s * 32 + ((l >> 4) * 8);
    #pragma unroll
    for (int j = 0; j < 8; j++) {
        int kh = kb + j;
        u16 v = 0;
        if (remap) {
            int jj = kh / JBLK, cc = kh - jj * JBLK;
            if (cc < CF) v = f2bf(w[(size_t)o * Cin + jj * CF + cc]);
        } else {
            if (kh < Cin) v = f2bf(w[(size_t)o * Cin + kh]);
        }
        out[(size_t)tid * 8 + j] = v;
    }
}

// ---------------------------------------------------------------------------
// Core: gather (pipelined DMA) + weight-net + einsum + MFMA GEMM vs lwP.
// Returns raw MFMA accumulators (tiles wv and wv+4).
__device__ __forceinline__ void pc_core(
    u16* __restrict__ smem,
    const u16* __restrict__ fcT, const float* __restrict__ xyzF,
    const int* __restrict__ knn, const float* __restrict__ wn_w,
    const float* __restrict__ wn_b, const u16* __restrict__ lwP,
    int pt0, int b, int n0, f32x4& acc1o, f32x4& acc2o)
{
    int t = threadIdx.x;
    int wv = t >> 6, lane = t & 63;
    int p = t >> 4, cl = t & 15;
    u16* rb16 = smem + RBOFF;

    // ---- P0 (wave-local): indices, rel coords, weight-net -> bf16 LDS ----
    {
        size_t rowC = (size_t)b * NPTS + n0 + p;
        int idxv = knn[rowC * KNN + cl];
        int rb = b * NPTS + idxv;
        rb16[p * 16 + cl] = (u16)rb;
        f32x4 cx = *(const f32x4*)(xyzF + rowC * 4);
        f32x4 nx = *(const f32x4*)(xyzF + (size_t)rb * 4);
        float rx = nx[0] - cx[0], ry = nx[1] - cx[1], rz = nx[2] - cx[2];
        unsigned int wp[4];
        #pragma unroll
        for (int jj = 0; jj < 4; jj++) {
            float a0 = lrelu(wn_w[(2 * jj) * 3 + 0] * rx + wn_w[(2 * jj) * 3 + 1] * ry +
                             wn_w[(2 * jj) * 3 + 2] * rz + wn_b[2 * jj]);
            float a1 = lrelu(wn_w[(2 * jj + 1) * 3 + 0] * rx + wn_w[(2 * jj + 1) * 3 + 1] * ry +
                             wn_w[(2 * jj + 1) * 3 + 2] * rz + wn_b[2 * jj + 1]);
            wp[jj] = (unsigned)f2bf(a0) | ((unsigned)f2bf(a1) << 16);
        }
        *(u32x4*)(smem + WOFF + (p * 16 + cl) * 8) = (u32x4){wp[0], wp[1], wp[2], wp[3]};
    }

    f32x2 acc[4][8];
    float acct[8];
    #pragma unroll
    for (int i = 0; i < 4; i++)
        #pragma unroll
        for (int j = 0; j < 8; j++) acc[i][j] = (f32x2){0.f, 0.f};
    #pragma unroll
    for (int j = 0; j < 8; j++) acct[j] = 0.f;

    // issue chunk c (4 k's for this wave's 4 points): 5 DMA insts/wave
    auto issue = [&](int c) {
        int h = c & 1;
        #pragma unroll
        for (int i = 0; i < 5; i++) {
            int slot = i * 64 + lane;
            if (i < 4 || lane < 16) {
                int rl = slot / 17;          // 0..15
                int rem = slot - rl * 17;    // 0..16
                int pp = wv * 4 + (rl >> 2);
                int kk = rl & 3;
                int rb = (int)rb16[pp * 16 + c * 4 + kk];
                dma16(fcT + (size_t)rb * ROW + rem * 8,
                      smem + h * HALF_U16 + (pp * 4 + kk) * 136 + rem * 8);
            }
        }
    };
    // consume chunk c: einsum over its 4 k's (LDS only)
    auto consume = [&](int c) {
        int h = c & 1;
        #pragma unroll
        for (int kk = 0; kk < 4; kk++) {
            const u16* rp = smem + h * HALF_U16 + (p * 4 + kk) * 136;
            u32x4 rv = *(const u32x4*)(rp + cl * 8);
            float tl = (cl < 3) ? b2f(rp[128 + cl]) : 0.0f;
            int k = c * 4 + kk;
            u32x4 wv4 = *(const u32x4*)(smem + WOFF + (p * 16 + k) * 8);
            f32x2 v[4];
            float wr[8];
            #pragma unroll
            for (int i = 0; i < 4; i++) {
                unsigned int u = rv[i];
                v[i] = (f32x2){__uint_as_float(u << 16),
                               __uint_as_float(u & 0xFFFF0000u)};
                unsigned int uw = wv4[i];
                wr[2 * i]     = __uint_as_float(uw << 16);
                wr[2 * i + 1] = __uint_as_float(uw & 0xFFFF0000u);
            }
            #pragma unroll
            for (int j = 0; j < 8; j++) {
                f32x2 w2 = (f32x2){wr[j], wr[j]};
                #pragma unroll
                for (int i = 0; i < 4; i++) acc[i][j] += v[i] * w2;
                acct[j] += tl * wr[j];
            }
        }
    };

    issue(0); issue(1);
    WAITVM(5); SB(); consume(0); SB(); issue(2); SB();
    WAITVM(5); SB(); consume(1); SB(); issue(3); SB();
    WAITVM(5); SB(); consume(2); SB();
    WAITVM(0); SB(); consume(3);
    __syncthreads();   // all einsum reads done before agg overwrites rowbuf

    // ---- agg write (bf16, k-hat layout) ----
    {
        #pragma unroll
        for (int j = 0; j < 8; j++) {
            unsigned int o[4];
            #pragma unroll
            for (int i = 0; i < 4; i++) {
                unsigned int lo = f2bf(acc[i][j].x);
                unsigned int hi = f2bf(acc[i][j].y);
                o[i] = lo | (hi << 16);
            }
            *(u32x4*)(smem + p * AGG_STRIDE + j * JBLK + cl * 8) =
                (u32x4){o[0], o[1], o[2], o[3]};
        }
        if (cl < 3) {
            #pragma unroll
            for (int j = 0; j < 8; j++)
                smem[p * AGG_STRIDE + j * JBLK + 128 + cl] = f2bf(acct[j]);
        }
        if (cl < 5) {
            #pragma unroll
            for (int j = 0; j < 8; j++)
                smem[p * AGG_STRIDE + j * JBLK + CF + cl] = 0;
        }
    }
    __syncthreads();

    // ---- MFMA: out[16][128] = agg @ lin_w^T ----
    {
        int m = lane & 15, quad = lane >> 4;
        f32x4 a1 = {0.f, 0.f, 0.f, 0.f};
        f32x4 a2 = {0.f, 0.f, 0.f, 0.f};
        for (int s = 0; s < NSTEP; s++) {
            u32x4 av = *(const u32x4*)(smem + m * AGG_STRIDE + s * 32 + quad * 8);
            u32x4 bv1 = *(const u32x4*)(lwP + (((size_t)(s * 8 + wv) * 64 + lane) << 3));
            u32x4 bv2 = *(const u32x4*)(lwP + (((size_t)(s * 8 + wv + 4) * 64 + lane) << 3));
            a1 = __builtin_amdgcn_mfma_f32_16x16x32_bf16(
                __builtin_bit_cast(bf16x8, av), __builtin_bit_cast(bf16x8, bv1), a1, 0, 0, 0);
            a2 = __builtin_amdgcn_mfma_f32_16x16x32_bf16(
                __builtin_bit_cast(bf16x8, av), __builtin_bit_cast(bf16x8, bv2), a2, 0, 0, 0);
        }
        acc1o = a1; acc2o = a2;
    }
}

// ---------------------------------------------------------------------------
// pc #1: writes bf16 rows into fcT2 at col offset 3.
__global__ __launch_bounds__(256, 4) void pc_kernel0(
    const u16* __restrict__ fcT, const float* __restrict__ xyzF,
    const int* __restrict__ knn, const float* __restrict__ wn_w,
    const float* __restrict__ wn_b, const u16* __restrict__ lwP,
    const float* __restrict__ lin_b, u16* __restrict__ out)
{
    __shared__ __align__(16) u16 smem[SMEM_U16];
    int t = threadIdx.x;
    int wv = t >> 6, lane = t & 63;
    int pt0 = blockIdx.x * 16;
    int b = pt0 >> 13;
    int n0 = pt0 & (NPTS - 1);
    f32x4 a1, a2;
    pc_core(smem, fcT, xyzF, knn, wn_w, wn_b, lwP, pt0, b, n0, a1, a2);
    int col = lane & 15, quad = lane >> 4;
    int o1 = wv * 16 + col, o2 = (wv + 4) * 16 + col;
    float bb1 = lin_b[o1], bb2 = lin_b[o2];
    #pragma unroll
    for (int r = 0; r < 4; r++) {
        int prow = pt0 + quad * 4 + r;
        out[(size_t)prow * ROW + 3 + o1] = f2bf(lrelu(a1[r] + bb1));
        out[(size_t)prow * ROW + 3 + o2] = f2bf(lrelu(a2[r] + bb2));
    }
}

// ---------------------------------------------------------------------------
// pc #2 fused with the MLP head: f2 stays in LDS; writes fp32 d_out.
__global__ __launch_bounds__(256, 3) void pc_kernel1(
    const u16* __restrict__ fcT, const float* __restrict__ xyzF,
    const int* __restrict__ knn, const float* __restrict__ wn_w,
    const float* __restrict__ wn_b, const u16* __restrict__ lwP,
    const float* __restrict__ lin_b,
    const u16* __restrict__ m1P, const float* __restrict__ m1_b,
    const u16* __restrict__ m2P, const float* __restrict__ m2_b,
    const float* __restrict__ cl_w, const float* __restrict__ cl_b,
    float* __restrict__ dout)
{
    __shared__ __align__(16) u16 smem[SMEM_U16];
    int t = threadIdx.x;
    int wv = t >> 6, lane = t & 63;
    int pt0 = blockIdx.x * 16;
    int b = pt0 >> 13;
    int n0 = pt0 & (NPTS - 1);
    f32x4 a1, a2;
    pc_core(smem, fcT, xyzF, knn, wn_w, wn_b, lwP, pt0, b, n0, a1, a2);
    int col = lane & 15, quad = lane >> 4;
    int m = lane & 15;

    // f2 tile -> LDS (agg region is done being read after this barrier)
    {
        int o1 = wv * 16 + col, o2 = (wv + 4) * 16 + col;
        float bb1 = lin_b[o1], bb2 = lin_b[o2];
        __syncthreads();
        #pragma unroll
        for (int r = 0; r < 4; r++) {
            int pr = quad * 4 + r;
            smem[F2T + pr * 128 + o1] = f2bf(lrelu(a1[r] + bb1));
            smem[F2T + pr * 128 + o2] = f2bf(lrelu(a2[r] + bb2));
        }
    }
    __syncthreads();

    // GEMM1: h1 = leaky(m1 @ f2 + b1) -> LDS
    {
        f32x4 g1 = {0.f, 0.f, 0.f, 0.f};
        f32x4 g2 = {0.f, 0.f, 0.f, 0.f};
        for (int s = 0; s < 4; s++) {
            u32x4 av = *(const u32x4*)(smem + F2T + m * 128 + s * 32 + quad * 8);
            u32x4 bv1 = *(const u32x4*)(m1P + (((size_t)(s * 8 + wv) * 64 + lane) << 3));
            u32x4 bv2 = *(const u32x4*)(m1P + (((size_t)(s * 8 + wv + 4) * 64 + lane) << 3));
            g1 = __builtin_amdgcn_mfma_f32_16x16x32_bf16(
                __builtin_bit_cast(bf16x8, av), __builtin_bit_cast(bf16x8, bv1), g1, 0, 0, 0);
            g2 = __builtin_amdgcn_mfma_f32_16x16x32_bf16(
                __builtin_bit_cast(bf16x8, av), __builtin_bit_cast(bf16x8, bv2), g2, 0, 0, 0);
        }
        int o1 = wv * 16 + col, o2 = (wv + 4) * 16 + col;
        float bb1 = m1_b[o1], bb2 = m1_b[o2];
        #pragma unroll
        for (int r = 0; r < 4; r++) {
            int pr = quad * 4 + r;
            smem[H1OFF + pr * 136 + o1] = f2bf(lrelu(g1[r] + bb1));
            smem[H1OFF + pr * 136 + o2] = f2bf(lrelu(g2[r] + bb2));
        }
    }
    __syncthreads();

    // GEMM2: flow_feat = leaky(m2 @ h1 + b2) -> d_out + ff (fp32 LDS)
    {
        float* ffp = (float*)(smem + FFOFF);
        f32x4 g = {0.f, 0.f, 0.f, 0.f};
        for (int s = 0; s < 4; s++) {
            u32x4 av = *(const u32x4*)(smem + H1OFF + m * 136 + s * 32 + quad * 8);
            u32x4 bv = *(const u32x4*)(m2P + (((size_t)(s * 4 + wv) * 64 + lane) << 3));
            g = __builtin_amdgcn_mfma_f32_16x16x32_bf16(
                __builtin_bit_cast(bf16x8, av), __builtin_bit_cast(bf16x8, bv), g, 0, 0, 0);
        }
        int o = wv * 16 + col;
        float bb = m2_b[o];
        #pragma unroll
        for (int r = 0; r < 4; r++) {
            int pr = quad * 4 + r;
            float v = lrelu(g[r] + bb);
            dout[((size_t)b * 64 + o) * NPTS + n0 + pr] = v;
            ffp[pr * 68 + o] = v;
        }
    }
    __syncthreads();

    // flow = cl_w @ ff + cl_b
    if (t < 48) {
        float* ffp = (float*)(smem + FFOFF);
        int pp = t & 15, oo = t >> 4;
        float a = cl_b[oo];
        #pragma unroll
        for (int i = 0; i < 64; i++)
            a += cl_w[oo * 64 + i] * ffp[pp * 68 + i];
        dout[(size_t)NB * 64 * NPTS + ((size_t)b * 3 + oo) * NPTS + n0 + pp] = a;
    }
}

// ---------------------------------------------------------------------------
extern "C" void kernel_launch(void* const* d_in, const int* in_sizes, int n_in,
                              void* d_out, int out_size, void* d_ws, size_t ws_size,
                              hipStream_t stream) {
    const float* xyz   = (const float*)d_in[0];
    const float* feat  = (const float*)d_in[1];
    const int*   knn   = (const int*)d_in[2];
    const float* wn1_w = (const float*)d_in[3];
    const float* wn1_b = (const float*)d_in[4];
    const float* lin1w = (const float*)d_in[5];
    const float* lin1b = (const float*)d_in[6];
    const float* wn2_w = (const float*)d_in[7];
    const float* wn2_b = (const float*)d_in[8];
    const float* lin2w = (const float*)d_in[9];
    const float* lin2b = (const float*)d_in[10];
    const float* m1_w  = (const float*)d_in[11];
    const float* m1_b  = (const float*)d_in[12];
    const float* m2_w  = (const float*)d_in[13];
    const float* m2_b  = (const float*)d_in[14];
    const float* cl_w  = (const float*)d_in[15];
    const float* cl_b  = (const float*)d_in[16];
    float* out = (float*)d_out;

    char* ws = (char*)d_ws;
    const size_t BN = (size_t)NB * NPTS;
    u16*   fcT1 = (u16*)(ws);                      // BN*136*2 = 8,912,896
    u16*   fcT2 = (u16*)(ws + 8912896);            // 8,912,896
    float* xyzF = (float*)(ws + 17825792);         // 524,288
    u16*   lw1P = (u16*)(ws + 18350080);           // 278,528
    u16*   lw2P = (u16*)(ws + 18628608);           // 278,528
    u16*   m1P  = (u16*)(ws + 18907136);           // 32,768
    u16*   m2P  = (u16*)(ws + 18939904);           // 16,384 -> total 18,956,288

    (void)in_sizes; (void)n_in; (void)out_size; (void)ws_size;

    pack_fcT<<<dim3(NB * (NPTS / 64)), dim3(256), 0, stream>>>(xyz, feat, fcT1, fcT2, xyzF);
    pack_wall<<<dim3(148), dim3(256), 0, stream>>>(lin1w, lin2w, m1_w, m2_w,
                                                   lw1P, lw2P, m1P, m2P);
    pc_kernel0<<<dim3(BN / 16), dim3(256), 0, stream>>>(
        fcT1, xyzF, knn, wn1_w, wn1_b, lw1P, lin1b, fcT2);
    pc_kernel1<<<dim3(BN / 16), dim3(256), 0, stream>>>(
        fcT2, xyzF, knn, wn2_w, wn2_b, lw2P, lin2b,
        m1P, m1_b, m2P, m2_b, cl_w, cl_b, out);
}

// Round 8
// 266.583 us; speedup vs baseline: 2.7399x; 2.7399x over previous
//
#include <hip/hip_runtime.h>

typedef __bf16 bf16x8 __attribute__((ext_vector_type(8)));
typedef float  f32x4  __attribute__((ext_vector_type(4)));
typedef float  f32x2  __attribute__((ext_vector_type(2)));
typedef unsigned int u32x4 __attribute__((ext_vector_type(4)));
typedef unsigned short u16;

#define NPTS 8192
#define NB   4
#define KNN  16
#define ROW  136        // u16 per row; 272 B = 17 x 16B
#define CF   131
#define JBLK 136
#define NSTEP 34        // K = 1088 = 34*32
#define AGG_STRIDE 1096 // u16 (2192 B per point)
#define HALF_U16 8704   // 64 rows * 136 u16 per ping-pong half
#define WOFF  17408     // u16 idx: w bf16 [16p][16k][8j]
#define RBOFF 19456     // u16 idx: rb table (u16[256])
#define SMEM_U16 19712  // 39424 B total
// mode-1 tail aliases (all inside dead rowbuf/agg region)
#define F2T   0         // u16[16][128]
#define H1OFF 2304      // u16, stride 136
#define FFOFF 4608      // u16 idx -> float* (byte 9216), stride 68 floats
#define NEG 0.1f

#define WAITVM(n) __builtin_amdgcn_s_waitcnt(0x0F70 | (n))
#define SB() __builtin_amdgcn_sched_barrier(0)

__device__ __forceinline__ float b2f(u16 h) {
    return __uint_as_float(((unsigned int)h) << 16);
}
__device__ __forceinline__ u16 f2bf(float f) {
    unsigned int u = __float_as_uint(f);
    unsigned int r = (u + 0x7FFFu + ((u >> 16) & 1u)) >> 16;
    return (u16)r;
}
__device__ __forceinline__ void dma16(const u16* g, u16* l) {
    __builtin_amdgcn_global_load_lds(
        (const __attribute__((address_space(1))) void*)g,
        (__attribute__((address_space(3))) void*)l, 16, 0, 0);
}
__device__ __forceinline__ float lrelu(float v) {
    return (v < 0.0f) ? NEG * v : v;
}

// ---------------------------------------------------------------------------
__global__ __launch_bounds__(256) void pack_fcT(
    const float* __restrict__ xyz, const float* __restrict__ feat,
    u16* __restrict__ fcT1, u16* __restrict__ fcT2, float* __restrict__ xyzF)
{
    __shared__ u16 tile[CF * 65];
    int t = threadIdx.x;
    int blk = blockIdx.x;
    int b = blk >> 7;
    int n0 = (blk & 127) << 6;
    int nn = t & 63;
    for (int c = (t >> 6); c < CF; c += 4) {
        float v;
        if (c < 3) v = xyz[(size_t)b * 3 * NPTS + (size_t)c * NPTS + n0 + nn];
        else       v = feat[(size_t)b * 128 * NPTS + (size_t)(c - 3) * NPTS + n0 + nn];
        tile[c * 65 + nn] = f2bf(v);
        if (c < 3) xyzF[((size_t)b * NPTS + n0 + nn) * 4 + c] = v;
    }
    __syncthreads();
    for (int e = t; e < 64 * ROW; e += 256) {
        int r = e / ROW;
        int c = e - r * ROW;
        u16 v = (c < CF) ? tile[c * 65 + r] : (u16)0;
        size_t row = (size_t)b * NPTS + n0 + r;
        fcT1[row * ROW + c] = v;
        if (c < 3 || c >= CF) fcT2[row * ROW + c] = v;
    }
}

// ---------------------------------------------------------------------------
// All four weight packs in one launch. Segments: [0,68) lw1, [68,136) lw2,
// [136,144) m1, [144,148) m2.
__global__ __launch_bounds__(256) void pack_wall(
    const float* __restrict__ l1, const float* __restrict__ l2,
    const float* __restrict__ w1, const float* __restrict__ w2,
    u16* __restrict__ o1, u16* __restrict__ o2,
    u16* __restrict__ o3, u16* __restrict__ o4)
{
    int blk = blockIdx.x;
    const float* w; u16* out; int O, Cin, remap, b0;
    if (blk < 68)       { w = l1; out = o1; O = 128; Cin = 1048; remap = 1; b0 = 0; }
    else if (blk < 136) { w = l2; out = o2; O = 128; Cin = 1048; remap = 1; b0 = 68; }
    else if (blk < 144) { w = w1; out = o3; O = 128; Cin = 128;  remap = 0; b0 = 136; }
    else                { w = w2; out = o4; O = 64;  Cin = 128;  remap = 0; b0 = 144; }
    int T = O >> 4;
    int tid = (blk - b0) * 256 + threadIdx.x;
    int l = tid & 63;
    int st = tid >> 6;
    int tt = st % T;
    int s = st / T;
    int o = tt * 16 + (l & 15);
    int kb = s * 32 + ((l >> 4) * 8);
    #pragma unroll
    for (int j = 0; j < 8; j++) {
        int kh = kb + j;
        u16 v = 0;
        if (remap) {
            int jj = kh / JBLK, cc = kh - jj * JBLK;
            if (cc < CF) v = f2bf(w[(size_t)o * Cin + jj * CF + cc]);
        } else {
            if (kh < Cin) v = f2bf(w[(size_t)o * Cin + kh]);
        }
        out[(size_t)tid * 8 + j] = v;
    }
}

// ---------------------------------------------------------------------------
// Core: gather (pipelined DMA) + weight-net + einsum + MFMA GEMM vs lwP.
// Returns raw MFMA accumulators (tiles wv and wv+4).
__device__ __forceinline__ void pc_core(
    u16* __restrict__ smem,
    const u16* __restrict__ fcT, const float* __restrict__ xyzF,
    const int* __restrict__ knn, const float* __restrict__ wn_w,
    const float* __restrict__ wn_b, const u16* __restrict__ lwP,
    int pt0, int b, int n0, f32x4& acc1o, f32x4& acc2o)
{
    int t = threadIdx.x;
    int wv = t >> 6, lane = t & 63;
    int p = t >> 4, cl = t & 15;
    u16* rb16 = smem + RBOFF;

    // ---- P0 (wave-local): indices, rel coords, weight-net -> bf16 LDS ----
    {
        size_t rowC = (size_t)b * NPTS + n0 + p;
        int idxv = knn[rowC * KNN + cl];
        int rb = b * NPTS + idxv;
        rb16[p * 16 + cl] = (u16)rb;
        f32x4 cx = *(const f32x4*)(xyzF + rowC * 4);
        f32x4 nx = *(const f32x4*)(xyzF + (size_t)rb * 4);
        float rx = nx[0] - cx[0], ry = nx[1] - cx[1], rz = nx[2] - cx[2];
        unsigned int wp[4];
        #pragma unroll
        for (int jj = 0; jj < 4; jj++) {
            float a0 = lrelu(wn_w[(2 * jj) * 3 + 0] * rx + wn_w[(2 * jj) * 3 + 1] * ry +
                             wn_w[(2 * jj) * 3 + 2] * rz + wn_b[2 * jj]);
            float a1 = lrelu(wn_w[(2 * jj + 1) * 3 + 0] * rx + wn_w[(2 * jj + 1) * 3 + 1] * ry +
                             wn_w[(2 * jj + 1) * 3 + 2] * rz + wn_b[2 * jj + 1]);
            wp[jj] = (unsigned)f2bf(a0) | ((unsigned)f2bf(a1) << 16);
        }
        *(u32x4*)(smem + WOFF + (p * 16 + cl) * 8) = (u32x4){wp[0], wp[1], wp[2], wp[3]};
    }

    f32x2 acc[4][8];
    float acct[8];
    #pragma unroll
    for (int i = 0; i < 4; i++)
        #pragma unroll
        for (int j = 0; j < 8; j++) acc[i][j] = (f32x2){0.f, 0.f};
    #pragma unroll
    for (int j = 0; j < 8; j++) acct[j] = 0.f;

    // issue chunk c (4 k's for this wave's 4 points): 5 DMA insts/wave
    auto issue = [&](int c) {
        int h = c & 1;
        #pragma unroll
        for (int i = 0; i < 5; i++) {
            int slot = i * 64 + lane;
            if (i < 4 || lane < 16) {
                int rl = slot / 17;          // 0..15
                int rem = slot - rl * 17;    // 0..16
                int pp = wv * 4 + (rl >> 2);
                int kk = rl & 3;
                int rb = (int)rb16[pp * 16 + c * 4 + kk];
                dma16(fcT + (size_t)rb * ROW + rem * 8,
                      smem + h * HALF_U16 + (pp * 4 + kk) * 136 + rem * 8);
            }
        }
    };
    // consume chunk c: einsum over its 4 k's (LDS only)
    auto consume = [&](int c) {
        int h = c & 1;
        #pragma unroll
        for (int kk = 0; kk < 4; kk++) {
            const u16* rp = smem + h * HALF_U16 + (p * 4 + kk) * 136;
            u32x4 rv = *(const u32x4*)(rp + cl * 8);
            float tl = (cl < 3) ? b2f(rp[128 + cl]) : 0.0f;
            int k = c * 4 + kk;
            u32x4 wv4 = *(const u32x4*)(smem + WOFF + (p * 16 + k) * 8);
            f32x2 v[4];
            float wr[8];
            #pragma unroll
            for (int i = 0; i < 4; i++) {
                unsigned int u = rv[i];
                v[i] = (f32x2){__uint_as_float(u << 16),
                               __uint_as_float(u & 0xFFFF0000u)};
                unsigned int uw = wv4[i];
                wr[2 * i]     = __uint_as_float(uw << 16);
                wr[2 * i + 1] = __uint_as_float(uw & 0xFFFF0000u);
            }
            #pragma unroll
            for (int j = 0; j < 8; j++) {
                f32x2 w2 = (f32x2){wr[j], wr[j]};
                #pragma unroll
                for (int i = 0; i < 4; i++) acc[i][j] += v[i] * w2;
                acct[j] += tl * wr[j];
            }
        }
    };

    issue(0); issue(1);
    WAITVM(5); SB(); consume(0); SB(); issue(2); SB();
    WAITVM(5); SB(); consume(1); SB(); issue(3); SB();
    WAITVM(5); SB(); consume(2); SB();
    WAITVM(0); SB(); consume(3);
    __syncthreads();   // all einsum reads done before agg overwrites rowbuf

    // ---- agg write (bf16, k-hat layout) ----
    {
        #pragma unroll
        for (int j = 0; j < 8; j++) {
            unsigned int o[4];
            #pragma unroll
            for (int i = 0; i < 4; i++) {
                unsigned int lo = f2bf(acc[i][j].x);
                unsigned int hi = f2bf(acc[i][j].y);
                o[i] = lo | (hi << 16);
            }
            *(u32x4*)(smem + p * AGG_STRIDE + j * JBLK + cl * 8) =
                (u32x4){o[0], o[1], o[2], o[3]};
        }
        if (cl < 3) {
            #pragma unroll
            for (int j = 0; j < 8; j++)
                smem[p * AGG_STRIDE + j * JBLK + 128 + cl] = f2bf(acct[j]);
        }
        if (cl < 5) {
            #pragma unroll
            for (int j = 0; j < 8; j++)
                smem[p * AGG_STRIDE + j * JBLK + CF + cl] = 0;
        }
    }
    __syncthreads();

    // ---- MFMA: out[16][128] = agg @ lin_w^T ----
    {
        int m = lane & 15, quad = lane >> 4;
        f32x4 a1 = {0.f, 0.f, 0.f, 0.f};
        f32x4 a2 = {0.f, 0.f, 0.f, 0.f};
        for (int s = 0; s < NSTEP; s++) {
            u32x4 av = *(const u32x4*)(smem + m * AGG_STRIDE + s * 32 + quad * 8);
            u32x4 bv1 = *(const u32x4*)(lwP + (((size_t)(s * 8 + wv) * 64 + lane) << 3));
            u32x4 bv2 = *(const u32x4*)(lwP + (((size_t)(s * 8 + wv + 4) * 64 + lane) << 3));
            a1 = __builtin_amdgcn_mfma_f32_16x16x32_bf16(
                __builtin_bit_cast(bf16x8, av), __builtin_bit_cast(bf16x8, bv1), a1, 0, 0, 0);
            a2 = __builtin_amdgcn_mfma_f32_16x16x32_bf16(
                __builtin_bit_cast(bf16x8, av), __builtin_bit_cast(bf16x8, bv2), a2, 0, 0, 0);
        }
        acc1o = a1; acc2o = a2;
    }
}

// ---------------------------------------------------------------------------
// pc #1: writes bf16 rows into fcT2 at col offset 3.
__global__ __launch_bounds__(256) void pc_kernel0(
    const u16* __restrict__ fcT, const float* __restrict__ xyzF,
    const int* __restrict__ knn, const float* __restrict__ wn_w,
    const float* __restrict__ wn_b, const u16* __restrict__ lwP,
    const float* __restrict__ lin_b, u16* __restrict__ out)
{
    __shared__ __align__(16) u16 smem[SMEM_U16];
    int t = threadIdx.x;
    int wv = t >> 6, lane = t & 63;
    int pt0 = blockIdx.x * 16;
    int b = pt0 >> 13;
    int n0 = pt0 & (NPTS - 1);
    f32x4 a1, a2;
    pc_core(smem, fcT, xyzF, knn, wn_w, wn_b, lwP, pt0, b, n0, a1, a2);
    int col = lane & 15, quad = lane >> 4;
    int o1 = wv * 16 + col, o2 = (wv + 4) * 16 + col;
    float bb1 = lin_b[o1], bb2 = lin_b[o2];
    #pragma unroll
    for (int r = 0; r < 4; r++) {
        int prow = pt0 + quad * 4 + r;
        out[(size_t)prow * ROW + 3 + o1] = f2bf(lrelu(a1[r] + bb1));
        out[(size_t)prow * ROW + 3 + o2] = f2bf(lrelu(a2[r] + bb2));
    }
}

// ---------------------------------------------------------------------------
// pc #2 fused with the MLP head: f2 stays in LDS; writes fp32 d_out.
__global__ __launch_bounds__(256) void pc_kernel1(
    const u16* __restrict__ fcT, const float* __restrict__ xyzF,
    const int* __restrict__ knn, const float* __restrict__ wn_w,
    const float* __restrict__ wn_b, const u16* __restrict__ lwP,
    const float* __restrict__ lin_b,
    const u16* __restrict__ m1P, const float* __restrict__ m1_b,
    const u16* __restrict__ m2P, const float* __restrict__ m2_b,
    const float* __restrict__ cl_w, const float* __restrict__ cl_b,
    float* __restrict__ dout)
{
    __shared__ __align__(16) u16 smem[SMEM_U16];
    int t = threadIdx.x;
    int wv = t >> 6, lane = t & 63;
    int pt0 = blockIdx.x * 16;
    int b = pt0 >> 13;
    int n0 = pt0 & (NPTS - 1);
    f32x4 a1, a2;
    pc_core(smem, fcT, xyzF, knn, wn_w, wn_b, lwP, pt0, b, n0, a1, a2);
    int col = lane & 15, quad = lane >> 4;
    int m = lane & 15;

    // f2 tile -> LDS (agg region is done being read after this barrier)
    {
        int o1 = wv * 16 + col, o2 = (wv + 4) * 16 + col;
        float bb1 = lin_b[o1], bb2 = lin_b[o2];
        __syncthreads();
        #pragma unroll
        for (int r = 0; r < 4; r++) {
            int pr = quad * 4 + r;
            smem[F2T + pr * 128 + o1] = f2bf(lrelu(a1[r] + bb1));
            smem[F2T + pr * 128 + o2] = f2bf(lrelu(a2[r] + bb2));
        }
    }
    __syncthreads();

    // GEMM1: h1 = leaky(m1 @ f2 + b1) -> LDS
    {
        f32x4 g1 = {0.f, 0.f, 0.f, 0.f};
        f32x4 g2 = {0.f, 0.f, 0.f, 0.f};
        for (int s = 0; s < 4; s++) {
            u32x4 av = *(const u32x4*)(smem + F2T + m * 128 + s * 32 + quad * 8);
            u32x4 bv1 = *(const u32x4*)(m1P + (((size_t)(s * 8 + wv) * 64 + lane) << 3));
            u32x4 bv2 = *(const u32x4*)(m1P + (((size_t)(s * 8 + wv + 4) * 64 + lane) << 3));
            g1 = __builtin_amdgcn_mfma_f32_16x16x32_bf16(
                __builtin_bit_cast(bf16x8, av), __builtin_bit_cast(bf16x8, bv1), g1, 0, 0, 0);
            g2 = __builtin_amdgcn_mfma_f32_16x16x32_bf16(
                __builtin_bit_cast(bf16x8, av), __builtin_bit_cast(bf16x8, bv2), g2, 0, 0, 0);
        }
        int o1 = wv * 16 + col, o2 = (wv + 4) * 16 + col;
        float bb1 = m1_b[o1], bb2 = m1_b[o2];
        #pragma unroll
        for (int r = 0; r < 4; r++) {
            int pr = quad * 4 + r;
            smem[H1OFF + pr * 136 + o1] = f2bf(lrelu(g1[r] + bb1));
            smem[H1OFF + pr * 136 + o2] = f2bf(lrelu(g2[r] + bb2));
        }
    }
    __syncthreads();

    // GEMM2: flow_feat = leaky(m2 @ h1 + b2) -> d_out + ff (fp32 LDS)
    {
        float* ffp = (float*)(smem + FFOFF);
        f32x4 g = {0.f, 0.f, 0.f, 0.f};
        for (int s = 0; s < 4; s++) {
            u32x4 av = *(const u32x4*)(smem + H1OFF + m * 136 + s * 32 + quad * 8);
            u32x4 bv = *(const u32x4*)(m2P + (((size_t)(s * 4 + wv) * 64 + lane) << 3));
            g = __builtin_amdgcn_mfma_f32_16x16x32_bf16(
                __builtin_bit_cast(bf16x8, av), __builtin_bit_cast(bf16x8, bv), g, 0, 0, 0);
        }
        int o = wv * 16 + col;
        float bb = m2_b[o];
        #pragma unroll
        for (int r = 0; r < 4; r++) {
            int pr = quad * 4 + r;
            float v = lrelu(g[r] + bb);
            dout[((size_t)b * 64 + o) * NPTS + n0 + pr] = v;
            ffp[pr * 68 + o] = v;
        }
    }
    __syncthreads();

    // flow = cl_w @ ff + cl_b
    if (t < 48) {
        float* ffp = (float*)(smem + FFOFF);
        int pp = t & 15, oo = t >> 4;
        float a = cl_b[oo];
        #pragma unroll
        for (int i = 0; i < 64; i++)
            a += cl_w[oo * 64 + i] * ffp[pp * 68 + i];
        dout[(size_t)NB * 64 * NPTS + ((size_t)b * 3 + oo) * NPTS + n0 + pp] = a;
    }
}

// ---------------------------------------------------------------------------
extern "C" void kernel_launch(void* const* d_in, const int* in_sizes, int n_in,
                              void* d_out, int out_size, void* d_ws, size_t ws_size,
                              hipStream_t stream) {
    const float* xyz   = (const float*)d_in[0];
    const float* feat  = (const float*)d_in[1];
    const int*   knn   = (const int*)d_in[2];
    const float* wn1_w = (const float*)d_in[3];
    const float* wn1_b = (const float*)d_in[4];
    const float* lin1w = (const float*)d_in[5];
    const float* lin1b = (const float*)d_in[6];
    const float* wn2_w = (const float*)d_in[7];
    const float* wn2_b = (const float*)d_in[8];
    const float* lin2w = (const float*)d_in[9];
    const float* lin2b = (const float*)d_in[10];
    const float* m1_w  = (const float*)d_in[11];
    const float* m1_b  = (const float*)d_in[12];
    const float* m2_w  = (const float*)d_in[13];
    const float* m2_b  = (const float*)d_in[14];
    const float* cl_w  = (const float*)d_in[15];
    const float* cl_b  = (const float*)d_in[16];
    float* out = (float*)d_out;

    char* ws = (char*)d_ws;
    const size_t BN = (size_t)NB * NPTS;
    u16*   fcT1 = (u16*)(ws);                      // BN*136*2 = 8,912,896
    u16*   fcT2 = (u16*)(ws + 8912896);            // 8,912,896
    float* xyzF = (float*)(ws + 17825792);         // 524,288
    u16*   lw1P = (u16*)(ws + 18350080);           // 278,528
    u16*   lw2P = (u16*)(ws + 18628608);           // 278,528
    u16*   m1P  = (u16*)(ws + 18907136);           // 32,768
    u16*   m2P  = (u16*)(ws + 18939904);           // 16,384 -> total 18,956,288

    (void)in_sizes; (void)n_in; (void)out_size; (void)ws_size;

    pack_fcT<<<dim3(NB * (NPTS / 64)), dim3(256), 0, stream>>>(xyz, feat, fcT1, fcT2, xyzF);
    pack_wall<<<dim3(148), dim3(256), 0, stream>>>(lin1w, lin2w, m1_w, m2_w,
                                                   lw1P, lw2P, m1P, m2P);
    pc_kernel0<<<dim3(BN / 16), dim3(256), 0, stream>>>(
        fcT1, xyzF, knn, wn1_w, wn1_b, lw1P, lin1b, fcT2);
    pc_kernel1<<<dim3(BN / 16), dim3(256), 0, stream>>>(
        fcT2, xyzF, knn, wn2_w, wn2_b, lw2P, lin2b,
        m1P, m1_b, m2P, m2_b, cl_w, cl_b, out);
}

// Round 9
// 203.191 us; speedup vs baseline: 3.5947x; 1.3120x over previous
//
#include <hip/hip_runtime.h>

typedef __bf16 bf16x8 __attribute__((ext_vector_type(8)));
typedef float  f32x4  __attribute__((ext_vector_type(4)));
typedef float  f32x2  __attribute__((ext_vector_type(2)));
typedef unsigned int u32x4 __attribute__((ext_vector_type(4)));
typedef unsigned short u16;

#define NPTS 8192
#define NB   4
#define KNN  16
#define ROW  136        // u16 per row; 272 B = 17 x 16B
#define CF   131
#define JBLK 136
#define NSTEP 34        // K = 1088 = 34*32
#define AGG_STRIDE 1096 // u16 (2192 B per point)
#define HALF_U16 8704   // 64 rows * 136 u16 per ping-pong half
#define WOFF  17408     // u16 idx: w bf16 [16p][16k][8j]
#define RBOFF 19456     // u16 idx: rb table (u16[256])
#define SMEM_U16 19712  // 39424 B total
// mode-1 tail aliases (all inside dead rowbuf/agg region)
#define F2T   0         // u16[16][128]
#define H1OFF 2304      // u16, stride 136
#define FFOFF 4608      // u16 idx -> float* (byte 9216), stride 68 floats
#define NEG 0.1f

#define WAITVM(n) __builtin_amdgcn_s_waitcnt(0x0F70 | (n))
#define SB() __builtin_amdgcn_sched_barrier(0)

__device__ __forceinline__ float b2f(u16 h) {
    return __uint_as_float(((unsigned int)h) << 16);
}
__device__ __forceinline__ u16 f2bf(float f) {
    unsigned int u = __float_as_uint(f);
    unsigned int r = (u + 0x7FFFu + ((u >> 16) & 1u)) >> 16;
    return (u16)r;
}
__device__ __forceinline__ void dma16(const u16* g, u16* l) {
    __builtin_amdgcn_global_load_lds(
        (const __attribute__((address_space(1))) void*)g,
        (__attribute__((address_space(3))) void*)l, 16, 0, 0);
}
__device__ __forceinline__ float lrelu(float v) {
    return (v < 0.0f) ? NEG * v : v;
}

// ---------------------------------------------------------------------------
__global__ __launch_bounds__(256) void pack_fcT(
    const float* __restrict__ xyz, const float* __restrict__ feat,
    u16* __restrict__ fcT1, u16* __restrict__ fcT2, float* __restrict__ xyzF)
{
    __shared__ u16 tile[CF * 65];
    int t = threadIdx.x;
    int blk = blockIdx.x;
    int b = blk >> 7;
    int n0 = (blk & 127) << 6;
    int nn = t & 63;
    #pragma unroll 1
    for (int c = (t >> 6); c < CF; c += 4) {
        float v;
        if (c < 3) v = xyz[(size_t)b * 3 * NPTS + (size_t)c * NPTS + n0 + nn];
        else       v = feat[(size_t)b * 128 * NPTS + (size_t)(c - 3) * NPTS + n0 + nn];
        tile[c * 65 + nn] = f2bf(v);
        if (c < 3) xyzF[((size_t)b * NPTS + n0 + nn) * 4 + c] = v;
    }
    __syncthreads();
    #pragma unroll 1
    for (int e = t; e < 64 * ROW; e += 256) {
        int r = e / ROW;
        int c = e - r * ROW;
        u16 v = (c < CF) ? tile[c * 65 + r] : (u16)0;
        size_t row = (size_t)b * NPTS + n0 + r;
        fcT1[row * ROW + c] = v;
        if (c < 3 || c >= CF) fcT2[row * ROW + c] = v;
    }
}

// ---------------------------------------------------------------------------
__global__ __launch_bounds__(256) void pack_wall(
    const float* __restrict__ l1, const float* __restrict__ l2,
    const float* __restrict__ w1, const float* __restrict__ w2,
    u16* __restrict__ o1, u16* __restrict__ o2,
    u16* __restrict__ o3, u16* __restrict__ o4)
{
    int blk = blockIdx.x;
    const float* w; u16* out; int O, Cin, remap, b0;
    if (blk < 68)       { w = l1; out = o1; O = 128; Cin = 1048; remap = 1; b0 = 0; }
    else if (blk < 136) { w = l2; out = o2; O = 128; Cin = 1048; remap = 1; b0 = 68; }
    else if (blk < 144) { w = w1; out = o3; O = 128; Cin = 128;  remap = 0; b0 = 136; }
    else                { w = w2; out = o4; O = 64;  Cin = 128;  remap = 0; b0 = 144; }
    int T = O >> 4;
    int tid = (blk - b0) * 256 + threadIdx.x;
    int l = tid & 63;
    int st = tid >> 6;
    int tt = st % T;
    int s = st / T;
    int o = tt * 16 + (l & 15);
    int kb = s * 32 + ((l >> 4) * 8);
    #pragma unroll 1
    for (int j = 0; j < 8; j++) {
        int kh = kb + j;
        u16 v = 0;
        if (remap) {
            int jj = kh / JBLK, cc = kh - jj * JBLK;
            if (cc < CF) v = f2bf(w[(size_t)o * Cin + jj * CF + cc]);
        } else {
            if (kh < Cin) v = f2bf(w[(size_t)o * Cin + kh]);
        }
        out[(size_t)tid * 8 + j] = v;
    }
}

// ---------------------------------------------------------------------------
// Core: gather (pipelined DMA) + weight-net + einsum + MFMA GEMM vs lwP.
// ROLLED loops everywhere except register-indexed accumulator dims.
__device__ __forceinline__ void pc_core(
    u16* __restrict__ smem,
    const u16* __restrict__ fcT, const float* __restrict__ xyzF,
    const int* __restrict__ knn, const float* __restrict__ wn_w,
    const float* __restrict__ wn_b, const u16* __restrict__ lwP,
    int pt0, int b, int n0, f32x4& acc1o, f32x4& acc2o)
{
    int t = threadIdx.x;
    int wv = t >> 6, lane = t & 63;
    int p = t >> 4, cl = t & 15;
    u16* rb16 = smem + RBOFF;

    // ---- P0 (wave-local): indices, rel coords, weight-net -> bf16 LDS ----
    {
        size_t rowC = (size_t)b * NPTS + n0 + p;
        int idxv = knn[rowC * KNN + cl];
        int rb = b * NPTS + idxv;
        rb16[p * 16 + cl] = (u16)rb;
        f32x4 cx = *(const f32x4*)(xyzF + rowC * 4);
        f32x4 nx = *(const f32x4*)(xyzF + (size_t)rb * 4);
        float rx = nx[0] - cx[0], ry = nx[1] - cx[1], rz = nx[2] - cx[2];
        unsigned int wp[4];
        #pragma unroll
        for (int jj = 0; jj < 4; jj++) {
            float a0 = lrelu(wn_w[(2 * jj) * 3 + 0] * rx + wn_w[(2 * jj) * 3 + 1] * ry +
                             wn_w[(2 * jj) * 3 + 2] * rz + wn_b[2 * jj]);
            float a1 = lrelu(wn_w[(2 * jj + 1) * 3 + 0] * rx + wn_w[(2 * jj + 1) * 3 + 1] * ry +
                             wn_w[(2 * jj + 1) * 3 + 2] * rz + wn_b[2 * jj + 1]);
            wp[jj] = (unsigned)f2bf(a0) | ((unsigned)f2bf(a1) << 16);
        }
        *(u32x4*)(smem + WOFF + (p * 16 + cl) * 8) = (u32x4){wp[0], wp[1], wp[2], wp[3]};
    }

    f32x2 acc[4][8];
    float acct[8];
    #pragma unroll
    for (int i = 0; i < 4; i++)
        #pragma unroll
        for (int j = 0; j < 8; j++) acc[i][j] = (f32x2){0.f, 0.f};
    #pragma unroll
    for (int j = 0; j < 8; j++) acct[j] = 0.f;

    // issue chunk c (4 k's for this wave's 4 points): 5 DMA insts/wave
    auto issue = [&](int c) {
        int h = c & 1;
        #pragma unroll 1
        for (int i = 0; i < 5; i++) {
            int slot = i * 64 + lane;
            if (i < 4 || lane < 16) {
                int rl = slot / 17;          // 0..15
                int rem = slot - rl * 17;    // 0..16
                int pp = wv * 4 + (rl >> 2);
                int kk = rl & 3;
                int rb = (int)rb16[pp * 16 + c * 4 + kk];
                dma16(fcT + (size_t)rb * ROW + rem * 8,
                      smem + h * HALF_U16 + (pp * 4 + kk) * 136 + rem * 8);
            }
        }
    };
    // consume chunk c: einsum over its 4 k's (LDS only). k-loop ROLLED.
    auto consume = [&](int c) {
        int h = c & 1;
        #pragma unroll 1
        for (int kk = 0; kk < 4; kk++) {
            const u16* rp = smem + h * HALF_U16 + (p * 4 + kk) * 136;
            u32x4 rv = *(const u32x4*)(rp + cl * 8);
            float tl = (cl < 3) ? b2f(rp[128 + cl]) : 0.0f;
            int k = c * 4 + kk;
            u32x4 wv4 = *(const u32x4*)(smem + WOFF + (p * 16 + k) * 8);
            f32x2 v[4];
            float wr[8];
            #pragma unroll
            for (int i = 0; i < 4; i++) {
                unsigned int u = rv[i];
                v[i] = (f32x2){__uint_as_float(u << 16),
                               __uint_as_float(u & 0xFFFF0000u)};
                unsigned int uw = wv4[i];
                wr[2 * i]     = __uint_as_float(uw << 16);
                wr[2 * i + 1] = __uint_as_float(uw & 0xFFFF0000u);
            }
            #pragma unroll
            for (int j = 0; j < 8; j++) {
                f32x2 w2 = (f32x2){wr[j], wr[j]};
                #pragma unroll
                for (int i = 0; i < 4; i++) acc[i][j] += v[i] * w2;
                acct[j] += tl * wr[j];
            }
        }
    };

    issue(0); issue(1);
    #pragma unroll 1
    for (int c = 0; c < 2; c++) {
        WAITVM(5); SB(); consume(c); SB(); issue(c + 2); SB();
    }
    WAITVM(5); SB(); consume(2); SB();
    WAITVM(0); SB(); consume(3);
    __syncthreads();   // all einsum reads done before agg overwrites rowbuf

    // ---- agg write (bf16, k-hat layout); j unrolled (acc indexing) ----
    {
        #pragma unroll
        for (int j = 0; j < 8; j++) {
            unsigned int o[4];
            #pragma unroll
            for (int i = 0; i < 4; i++) {
                unsigned int lo = f2bf(acc[i][j].x);
                unsigned int hi = f2bf(acc[i][j].y);
                o[i] = lo | (hi << 16);
            }
            *(u32x4*)(smem + p * AGG_STRIDE + j * JBLK + cl * 8) =
                (u32x4){o[0], o[1], o[2], o[3]};
        }
        if (cl < 3) {
            #pragma unroll
            for (int j = 0; j < 8; j++)
                smem[p * AGG_STRIDE + j * JBLK + 128 + cl] = f2bf(acct[j]);
        }
        if (cl < 5) {
            #pragma unroll
            for (int j = 0; j < 8; j++)
                smem[p * AGG_STRIDE + j * JBLK + CF + cl] = 0;
        }
    }
    __syncthreads();

    // ---- MFMA: out[16][128] = agg @ lin_w^T. Rolled, unroll-4 ----
    {
        int m = lane & 15, quad = lane >> 4;
        f32x4 a1 = {0.f, 0.f, 0.f, 0.f};
        f32x4 a2 = {0.f, 0.f, 0.f, 0.f};
        #pragma unroll 4
        for (int s = 0; s < NSTEP; s++) {
            u32x4 av = *(const u32x4*)(smem + m * AGG_STRIDE + s * 32 + quad * 8);
            u32x4 bv1 = *(const u32x4*)(lwP + (((size_t)(s * 8 + wv) * 64 + lane) << 3));
            u32x4 bv2 = *(const u32x4*)(lwP + (((size_t)(s * 8 + wv + 4) * 64 + lane) << 3));
            a1 = __builtin_amdgcn_mfma_f32_16x16x32_bf16(
                __builtin_bit_cast(bf16x8, av), __builtin_bit_cast(bf16x8, bv1), a1, 0, 0, 0);
            a2 = __builtin_amdgcn_mfma_f32_16x16x32_bf16(
                __builtin_bit_cast(bf16x8, av), __builtin_bit_cast(bf16x8, bv2), a2, 0, 0, 0);
        }
        acc1o = a1; acc2o = a2;
    }
}

// ---------------------------------------------------------------------------
// pc #1: writes bf16 rows into fcT2 at col offset 3.
__global__ __launch_bounds__(256) void pc_kernel0(
    const u16* __restrict__ fcT, const float* __restrict__ xyzF,
    const int* __restrict__ knn, const float* __restrict__ wn_w,
    const float* __restrict__ wn_b, const u16* __restrict__ lwP,
    const float* __restrict__ lin_b, u16* __restrict__ out)
{
    __shared__ __align__(16) u16 smem[SMEM_U16];
    int t = threadIdx.x;
    int wv = t >> 6, lane = t & 63;
    int pt0 = blockIdx.x * 16;
    int b = pt0 >> 13;
    int n0 = pt0 & (NPTS - 1);
    f32x4 a1, a2;
    pc_core(smem, fcT, xyzF, knn, wn_w, wn_b, lwP, pt0, b, n0, a1, a2);
    int col = lane & 15, quad = lane >> 4;
    int o1 = wv * 16 + col, o2 = (wv + 4) * 16 + col;
    float bb1 = lin_b[o1], bb2 = lin_b[o2];
    #pragma unroll
    for (int r = 0; r < 4; r++) {
        int prow = pt0 + quad * 4 + r;
        out[(size_t)prow * ROW + 3 + o1] = f2bf(lrelu(a1[r] + bb1));
        out[(size_t)prow * ROW + 3 + o2] = f2bf(lrelu(a2[r] + bb2));
    }
}

// ---------------------------------------------------------------------------
// pc #2 fused with the MLP head: f2 stays in LDS; writes fp32 d_out.
__global__ __launch_bounds__(256) void pc_kernel1(
    const u16* __restrict__ fcT, const float* __restrict__ xyzF,
    const int* __restrict__ knn, const float* __restrict__ wn_w,
    const float* __restrict__ wn_b, const u16* __restrict__ lwP,
    const float* __restrict__ lin_b,
    const u16* __restrict__ m1P, const float* __restrict__ m1_b,
    const u16* __restrict__ m2P, const float* __restrict__ m2_b,
    const float* __restrict__ cl_w, const float* __restrict__ cl_b,
    float* __restrict__ dout)
{
    __shared__ __align__(16) u16 smem[SMEM_U16];
    int t = threadIdx.x;
    int wv = t >> 6, lane = t & 63;
    int pt0 = blockIdx.x * 16;
    int b = pt0 >> 13;
    int n0 = pt0 & (NPTS - 1);
    f32x4 a1, a2;
    pc_core(smem, fcT, xyzF, knn, wn_w, wn_b, lwP, pt0, b, n0, a1, a2);
    int col = lane & 15, quad = lane >> 4;
    int m = lane & 15;

    // f2 tile -> LDS (agg region is done being read after this barrier)
    {
        int o1 = wv * 16 + col, o2 = (wv + 4) * 16 + col;
        float bb1 = lin_b[o1], bb2 = lin_b[o2];
        __syncthreads();
        #pragma unroll
        for (int r = 0; r < 4; r++) {
            int pr = quad * 4 + r;
            smem[F2T + pr * 128 + o1] = f2bf(lrelu(a1[r] + bb1));
            smem[F2T + pr * 128 + o2] = f2bf(lrelu(a2[r] + bb2));
        }
    }
    __syncthreads();

    // GEMM1: h1 = leaky(m1 @ f2 + b1) -> LDS
    {
        f32x4 g1 = {0.f, 0.f, 0.f, 0.f};
        f32x4 g2 = {0.f, 0.f, 0.f, 0.f};
        #pragma unroll 2
        for (int s = 0; s < 4; s++) {
            u32x4 av = *(const u32x4*)(smem + F2T + m * 128 + s * 32 + quad * 8);
            u32x4 bv1 = *(const u32x4*)(m1P + (((size_t)(s * 8 + wv) * 64 + lane) << 3));
            u32x4 bv2 = *(const u32x4*)(m1P + (((size_t)(s * 8 + wv + 4) * 64 + lane) << 3));
            g1 = __builtin_amdgcn_mfma_f32_16x16x32_bf16(
                __builtin_bit_cast(bf16x8, av), __builtin_bit_cast(bf16x8, bv1), g1, 0, 0, 0);
            g2 = __builtin_amdgcn_mfma_f32_16x16x32_bf16(
                __builtin_bit_cast(bf16x8, av), __builtin_bit_cast(bf16x8, bv2), g2, 0, 0, 0);
        }
        int o1 = wv * 16 + col, o2 = (wv + 4) * 16 + col;
        float bb1 = m1_b[o1], bb2 = m1_b[o2];
        #pragma unroll
        for (int r = 0; r < 4; r++) {
            int pr = quad * 4 + r;
            smem[H1OFF + pr * 136 + o1] = f2bf(lrelu(g1[r] + bb1));
            smem[H1OFF + pr * 136 + o2] = f2bf(lrelu(g2[r] + bb2));
        }
    }
    __syncthreads();

    // GEMM2: flow_feat = leaky(m2 @ h1 + b2) -> d_out + ff (fp32 LDS)
    {
        float* ffp = (float*)(smem + FFOFF);
        f32x4 g = {0.f, 0.f, 0.f, 0.f};
        #pragma unroll 2
        for (int s = 0; s < 4; s++) {
            u32x4 av = *(const u32x4*)(smem + H1OFF + m * 136 + s * 32 + quad * 8);
            u32x4 bv = *(const u32x4*)(m2P + (((size_t)(s * 4 + wv) * 64 + lane) << 3));
            g = __builtin_amdgcn_mfma_f32_16x16x32_bf16(
                __builtin_bit_cast(bf16x8, av), __builtin_bit_cast(bf16x8, bv), g, 0, 0, 0);
        }
        int o = wv * 16 + col;
        float bb = m2_b[o];
        #pragma unroll
        for (int r = 0; r < 4; r++) {
            int pr = quad * 4 + r;
            float v = lrelu(g[r] + bb);
            dout[((size_t)b * 64 + o) * NPTS + n0 + pr] = v;
            ffp[pr * 68 + o] = v;
        }
    }
    __syncthreads();

    // flow = cl_w @ ff + cl_b  (rolled)
    if (t < 48) {
        float* ffp = (float*)(smem + FFOFF);
        int pp = t & 15, oo = t >> 4;
        float a = cl_b[oo];
        #pragma unroll 8
        for (int i = 0; i < 64; i++)
            a += cl_w[oo * 64 + i] * ffp[pp * 68 + i];
        dout[(size_t)NB * 64 * NPTS + ((size_t)b * 3 + oo) * NPTS + n0 + pp] = a;
    }
}

// ---------------------------------------------------------------------------
extern "C" void kernel_launch(void* const* d_in, const int* in_sizes, int n_in,
                              void* d_out, int out_size, void* d_ws, size_t ws_size,
                              hipStream_t stream) {
    const float* xyz   = (const float*)d_in[0];
    const float* feat  = (const float*)d_in[1];
    const int*   knn   = (const int*)d_in[2];
    const float* wn1_w = (const float*)d_in[3];
    const float* wn1_b = (const float*)d_in[4];
    const float* lin1w = (const float*)d_in[5];
    const float* lin1b = (const float*)d_in[6];
    const float* wn2_w = (const float*)d_in[7];
    const float* wn2_b = (const float*)d_in[8];
    const float* lin2w = (const float*)d_in[9];
    const float* lin2b = (const float*)d_in[10];
    const float* m1_w  = (const float*)d_in[11];
    const float* m1_b  = (const float*)d_in[12];
    const float* m2_w  = (const float*)d_in[13];
    const float* m2_b  = (const float*)d_in[14];
    const float* cl_w  = (const float*)d_in[15];
    const float* cl_b  = (const float*)d_in[16];
    float* out = (float*)d_out;

    char* ws = (char*)d_ws;
    const size_t BN = (size_t)NB * NPTS;
    u16*   fcT1 = (u16*)(ws);                      // BN*136*2 = 8,912,896
    u16*   fcT2 = (u16*)(ws + 8912896);            // 8,912,896
    float* xyzF = (float*)(ws + 17825792);         // 524,288
    u16*   lw1P = (u16*)(ws + 18350080);           // 278,528
    u16*   lw2P = (u16*)(ws + 18628608);           // 278,528
    u16*   m1P  = (u16*)(ws + 18907136);           // 32,768
    u16*   m2P  = (u16*)(ws + 18939904);           // 16,384 -> total 18,956,288

    (void)in_sizes; (void)n_in; (void)out_size; (void)ws_size;

    pack_fcT<<<dim3(NB * (NPTS / 64)), dim3(256), 0, stream>>>(xyz, feat, fcT1, fcT2, xyzF);
    pack_wall<<<dim3(148), dim3(256), 0, stream>>>(lin1w, lin2w, m1_w, m2_w,
                                                   lw1P, lw2P, m1P, m2P);
    pc_kernel0<<<dim3(BN / 16), dim3(256), 0, stream>>>(
        fcT1, xyzF, knn, wn1_w, wn1_b, lw1P, lin1b, fcT2);
    pc_kernel1<<<dim3(BN / 16), dim3(256), 0, stream>>>(
        fcT2, xyzF, knn, wn2_w, wn2_b, lw2P, lin2b,
        m1P, m1_b, m2P, m2_b, cl_w, cl_b, out);
}

// Round 10
// 193.774 us; speedup vs baseline: 3.7694x; 1.0486x over previous
//
#include <hip/hip_runtime.h>

typedef __bf16 bf16x8 __attribute__((ext_vector_type(8)));
typedef float  f32x4  __attribute__((ext_vector_type(4)));
typedef float  f32x2  __attribute__((ext_vector_type(2)));
typedef unsigned int u32x4 __attribute__((ext_vector_type(4)));
typedef unsigned short u16;

#define NPTS 8192
#define NB   4
#define KNN  16
#define ROW  136        // u16 per row; 272 B = 17 x 16B
#define CF   131
#define JBLK 136
#define NSTEP 34        // K = 1088 = 34*32
#define AGG_STRIDE 1096 // u16 (2192 B per point)
#define HALF_U16 8704   // 64 rows * 136 u16 per ping-pong half
#define WOFF  17408     // u16 idx: w bf16 [16p][16k][8j]
#define RBOFF 19456     // u16 idx: rb table (u16[256])
#define SMEM_U16 19712  // 39424 B total
// mode-1 tail aliases (all inside dead rowbuf/agg region)
#define F2T   0         // u16[16][128]
#define H1OFF 2304      // u16, stride 136
#define FFOFF 4608      // u16 idx -> float* (byte 9216), stride 68 floats
#define NEG 0.1f

#define WAITVM(n) __builtin_amdgcn_s_waitcnt(0x0F70 | (n))
#define SB() __builtin_amdgcn_sched_barrier(0)

__device__ __forceinline__ float b2f(u16 h) {
    return __uint_as_float(((unsigned int)h) << 16);
}
// round-half-up: 2 insts (was 4 for RNE); <=1 ulp bf16, budget has 2.9x headroom
__device__ __forceinline__ u16 f2bf(float f) {
    unsigned int u = __float_as_uint(f);
    return (u16)((u + 0x8000u) >> 16);
}
__device__ __forceinline__ void dma16(const u16* g, u16* l) {
    __builtin_amdgcn_global_load_lds(
        (const __attribute__((address_space(1))) void*)g,
        (__attribute__((address_space(3))) void*)l, 16, 0, 0);
}
__device__ __forceinline__ float lrelu(float v) {
    return (v < 0.0f) ? NEG * v : v;
}

// ---------------------------------------------------------------------------
// Merged pack kernel. Blocks [0,512): fcT1/fcT2/xyzF pack.
// Blocks [512,660): weight packs (lw1 68, lw2 68, m1 8, m2 4).
__global__ __launch_bounds__(256) void pack_all(
    const float* __restrict__ xyz, const float* __restrict__ feat,
    u16* __restrict__ fcT1, u16* __restrict__ fcT2, float* __restrict__ xyzF,
    const float* __restrict__ l1, const float* __restrict__ l2,
    const float* __restrict__ w1, const float* __restrict__ w2,
    u16* __restrict__ o1, u16* __restrict__ o2,
    u16* __restrict__ o3, u16* __restrict__ o4)
{
    int t = threadIdx.x;
    if (blockIdx.x < 512) {
        __shared__ u16 tile[CF * 65];
        int blk = blockIdx.x;
        int b = blk >> 7;
        int n0 = (blk & 127) << 6;
        int nn = t & 63;
        #pragma unroll 1
        for (int c = (t >> 6); c < CF; c += 4) {
            float v;
            if (c < 3) v = xyz[(size_t)b * 3 * NPTS + (size_t)c * NPTS + n0 + nn];
            else       v = feat[(size_t)b * 128 * NPTS + (size_t)(c - 3) * NPTS + n0 + nn];
            tile[c * 65 + nn] = f2bf(v);
            if (c < 3) xyzF[((size_t)b * NPTS + n0 + nn) * 4 + c] = v;
        }
        __syncthreads();
        #pragma unroll 1
        for (int e = t; e < 64 * ROW; e += 256) {
            int r = e / ROW;
            int c = e - r * ROW;
            u16 v = (c < CF) ? tile[c * 65 + r] : (u16)0;
            size_t row = (size_t)b * NPTS + n0 + r;
            fcT1[row * ROW + c] = v;
            if (c < 3 || c >= CF) fcT2[row * ROW + c] = v;
        }
    } else {
        int blk = blockIdx.x - 512;
        const float* w; u16* out; int O, Cin, remap, b0;
        if (blk < 68)       { w = l1; out = o1; O = 128; Cin = 1048; remap = 1; b0 = 0; }
        else if (blk < 136) { w = l2; out = o2; O = 128; Cin = 1048; remap = 1; b0 = 68; }
        else if (blk < 144) { w = w1; out = o3; O = 128; Cin = 128;  remap = 0; b0 = 136; }
        else                { w = w2; out = o4; O = 64;  Cin = 128;  remap = 0; b0 = 144; }
        int T = O >> 4;
        int tid = (blk - b0) * 256 + t;
        int l = tid & 63;
        int st = tid >> 6;
        int tt = st % T;
        int s = st / T;
        int o = tt * 16 + (l & 15);
        int kb = s * 32 + ((l >> 4) * 8);
        #pragma unroll 1
        for (int j = 0; j < 8; j++) {
            int kh = kb + j;
            u16 v = 0;
            if (remap) {
                int jj = kh / JBLK, cc = kh - jj * JBLK;
                if (cc < CF) v = f2bf(w[(size_t)o * Cin + jj * CF + cc]);
            } else {
                if (kh < Cin) v = f2bf(w[(size_t)o * Cin + kh]);
            }
            out[(size_t)tid * 8 + j] = v;
        }
    }
}

// ---------------------------------------------------------------------------
// Core: gather (pipelined DMA) + weight-net + einsum + MFMA GEMM vs lwP.
__device__ __forceinline__ void pc_core(
    u16* __restrict__ smem,
    const u16* __restrict__ fcT, const float* __restrict__ xyzF,
    const int* __restrict__ knn, const float* __restrict__ wn_w,
    const float* __restrict__ wn_b, const u16* __restrict__ lwP,
    int pt0, int b, int n0, f32x4& acc1o, f32x4& acc2o)
{
    int t = threadIdx.x;
    int wv = t >> 6, lane = t & 63;
    int p = t >> 4, cl = t & 15;
    u16* rb16 = smem + RBOFF;

    // ---- P0 (wave-local): indices, rel coords, weight-net -> bf16 LDS ----
    {
        size_t rowC = (size_t)b * NPTS + n0 + p;
        int idxv = knn[rowC * KNN + cl];
        int rb = b * NPTS + idxv;
        rb16[p * 16 + cl] = (u16)rb;
        f32x4 cx = *(const f32x4*)(xyzF + rowC * 4);
        f32x4 nx = *(const f32x4*)(xyzF + (size_t)rb * 4);
        float rx = nx[0] - cx[0], ry = nx[1] - cx[1], rz = nx[2] - cx[2];
        unsigned int wp[4];
        #pragma unroll
        for (int jj = 0; jj < 4; jj++) {
            float a0 = lrelu(wn_w[(2 * jj) * 3 + 0] * rx + wn_w[(2 * jj) * 3 + 1] * ry +
                             wn_w[(2 * jj) * 3 + 2] * rz + wn_b[2 * jj]);
            float a1 = lrelu(wn_w[(2 * jj + 1) * 3 + 0] * rx + wn_w[(2 * jj + 1) * 3 + 1] * ry +
                             wn_w[(2 * jj + 1) * 3 + 2] * rz + wn_b[2 * jj + 1]);
            wp[jj] = (unsigned)f2bf(a0) | ((unsigned)f2bf(a1) << 16);
        }
        *(u32x4*)(smem + WOFF + (p * 16 + cl) * 8) = (u32x4){wp[0], wp[1], wp[2], wp[3]};
    }

    f32x2 acc[4][8];
    float acct[8];
    #pragma unroll
    for (int i = 0; i < 4; i++)
        #pragma unroll
        for (int j = 0; j < 8; j++) acc[i][j] = (f32x2){0.f, 0.f};
    #pragma unroll
    for (int j = 0; j < 8; j++) acct[j] = 0.f;

    // ---- hoisted DMA slot decomposition (chunk-invariant) ----
    int rbidx[5], remu[5], ldso[5];
    #pragma unroll
    for (int i = 0; i < 5; i++) {
        int slot = i * 64 + lane;
        int rl = slot / 17;              // 0..15 (row within wave's chunk)
        int rem = slot - rl * 17;        // 0..16 (16B unit within row)
        int pp = wv * 4 + (rl >> 2);
        int kk = rl & 3;
        rbidx[i] = pp * 16 + kk;         // + c*4 per chunk
        remu[i] = rem * 8;               // u16 offset in row
        ldso[i] = (pp * 4 + kk) * 136 + rem * 8;
    }

    auto issue = [&](int c) {
        int h = c & 1;
        #pragma unroll
        for (int i = 0; i < 5; i++) {
            if (i < 4 || lane < 16) {
                int rb = (int)rb16[rbidx[i] + c * 4];
                dma16(fcT + (size_t)rb * ROW + remu[i],
                      smem + h * HALF_U16 + ldso[i]);
            }
        }
    };
    // consume chunk c: einsum over its 4 k's (LDS only)
    auto consume = [&](int c) {
        int h = c & 1;
        const u16* rpb = smem + h * HALF_U16 + p * (4 * 136);
        const u16* wpb = smem + WOFF + (p * 16 + c * 4) * 8;
        #pragma unroll 2
        for (int kk = 0; kk < 4; kk++) {
            u32x4 rv = *(const u32x4*)(rpb + kk * 136 + cl * 8);
            float tl = (cl < 3) ? b2f(rpb[kk * 136 + 128 + cl]) : 0.0f;
            u32x4 wv4 = *(const u32x4*)(wpb + kk * 8);
            f32x2 v[4];
            float wr[8];
            #pragma unroll
            for (int i = 0; i < 4; i++) {
                unsigned int u = rv[i];
                v[i] = (f32x2){__uint_as_float(u << 16),
                               __uint_as_float(u & 0xFFFF0000u)};
                unsigned int uw = wv4[i];
                wr[2 * i]     = __uint_as_float(uw << 16);
                wr[2 * i + 1] = __uint_as_float(uw & 0xFFFF0000u);
            }
            #pragma unroll
            for (int j = 0; j < 8; j++) {
                f32x2 w2 = (f32x2){wr[j], wr[j]};
                #pragma unroll
                for (int i = 0; i < 4; i++) acc[i][j] += v[i] * w2;
                acct[j] += tl * wr[j];
            }
        }
    };

    issue(0); issue(1);
    #pragma unroll 1
    for (int c = 0; c < 2; c++) {
        WAITVM(5); SB(); consume(c); SB(); issue(c + 2); SB();
    }
    WAITVM(5); SB(); consume(2); SB();
    WAITVM(0); SB(); consume(3);
    __syncthreads();   // all einsum reads done before agg overwrites rowbuf

    // ---- agg write (bf16, k-hat layout) ----
    {
        #pragma unroll
        for (int j = 0; j < 8; j++) {
            unsigned int o[4];
            #pragma unroll
            for (int i = 0; i < 4; i++) {
                unsigned int lo = f2bf(acc[i][j].x);
                unsigned int hi = f2bf(acc[i][j].y);
                o[i] = lo | (hi << 16);
            }
            *(u32x4*)(smem + p * AGG_STRIDE + j * JBLK + cl * 8) =
                (u32x4){o[0], o[1], o[2], o[3]};
        }
        if (cl < 3) {
            #pragma unroll
            for (int j = 0; j < 8; j++)
                smem[p * AGG_STRIDE + j * JBLK + 128 + cl] = f2bf(acct[j]);
        }
        if (cl < 5) {
            #pragma unroll
            for (int j = 0; j < 8; j++)
                smem[p * AGG_STRIDE + j * JBLK + CF + cl] = 0;
        }
    }
    __syncthreads();

    // ---- MFMA: out[16][128] = agg @ lin_w^T. Rolled, unroll-4 ----
    {
        int m = lane & 15, quad = lane >> 4;
        f32x4 a1 = {0.f, 0.f, 0.f, 0.f};
        f32x4 a2 = {0.f, 0.f, 0.f, 0.f};
        #pragma unroll 4
        for (int s = 0; s < NSTEP; s++) {
            u32x4 av = *(const u32x4*)(smem + m * AGG_STRIDE + s * 32 + quad * 8);
            u32x4 bv1 = *(const u32x4*)(lwP + (((size_t)(s * 8 + wv) * 64 + lane) << 3));
            u32x4 bv2 = *(const u32x4*)(lwP + (((size_t)(s * 8 + wv + 4) * 64 + lane) << 3));
            a1 = __builtin_amdgcn_mfma_f32_16x16x32_bf16(
                __builtin_bit_cast(bf16x8, av), __builtin_bit_cast(bf16x8, bv1), a1, 0, 0, 0);
            a2 = __builtin_amdgcn_mfma_f32_16x16x32_bf16(
                __builtin_bit_cast(bf16x8, av), __builtin_bit_cast(bf16x8, bv2), a2, 0, 0, 0);
        }
        acc1o = a1; acc2o = a2;
    }
}

// ---------------------------------------------------------------------------
// pc #1: writes bf16 rows into fcT2 at col offset 3.
__global__ __launch_bounds__(256) void pc_kernel0(
    const u16* __restrict__ fcT, const float* __restrict__ xyzF,
    const int* __restrict__ knn, const float* __restrict__ wn_w,
    const float* __restrict__ wn_b, const u16* __restrict__ lwP,
    const float* __restrict__ lin_b, u16* __restrict__ out)
{
    __shared__ __align__(16) u16 smem[SMEM_U16];
    int t = threadIdx.x;
    int wv = t >> 6, lane = t & 63;
    int pt0 = blockIdx.x * 16;
    int b = pt0 >> 13;
    int n0 = pt0 & (NPTS - 1);
    f32x4 a1, a2;
    pc_core(smem, fcT, xyzF, knn, wn_w, wn_b, lwP, pt0, b, n0, a1, a2);
    int col = lane & 15, quad = lane >> 4;
    int o1 = wv * 16 + col, o2 = (wv + 4) * 16 + col;
    float bb1 = lin_b[o1], bb2 = lin_b[o2];
    #pragma unroll
    for (int r = 0; r < 4; r++) {
        int prow = pt0 + quad * 4 + r;
        out[(size_t)prow * ROW + 3 + o1] = f2bf(lrelu(a1[r] + bb1));
        out[(size_t)prow * ROW + 3 + o2] = f2bf(lrelu(a2[r] + bb2));
    }
}

// ---------------------------------------------------------------------------
// pc #2 fused with the MLP head: f2 stays in LDS; writes fp32 d_out.
__global__ __launch_bounds__(256) void pc_kernel1(
    const u16* __restrict__ fcT, const float* __restrict__ xyzF,
    const int* __restrict__ knn, const float* __restrict__ wn_w,
    const float* __restrict__ wn_b, const u16* __restrict__ lwP,
    const float* __restrict__ lin_b,
    const u16* __restrict__ m1P, const float* __restrict__ m1_b,
    const u16* __restrict__ m2P, const float* __restrict__ m2_b,
    const float* __restrict__ cl_w, const float* __restrict__ cl_b,
    float* __restrict__ dout)
{
    __shared__ __align__(16) u16 smem[SMEM_U16];
    int t = threadIdx.x;
    int wv = t >> 6, lane = t & 63;
    int pt0 = blockIdx.x * 16;
    int b = pt0 >> 13;
    int n0 = pt0 & (NPTS - 1);
    f32x4 a1, a2;
    pc_core(smem, fcT, xyzF, knn, wn_w, wn_b, lwP, pt0, b, n0, a1, a2);
    int col = lane & 15, quad = lane >> 4;
    int m = lane & 15;

    // f2 tile -> LDS (agg region is done being read after this barrier)
    {
        int o1 = wv * 16 + col, o2 = (wv + 4) * 16 + col;
        float bb1 = lin_b[o1], bb2 = lin_b[o2];
        __syncthreads();
        #pragma unroll
        for (int r = 0; r < 4; r++) {
            int pr = quad * 4 + r;
            smem[F2T + pr * 128 + o1] = f2bf(lrelu(a1[r] + bb1));
            smem[F2T + pr * 128 + o2] = f2bf(lrelu(a2[r] + bb2));
        }
    }
    __syncthreads();

    // GEMM1: h1 = leaky(m1 @ f2 + b1) -> LDS
    {
        f32x4 g1 = {0.f, 0.f, 0.f, 0.f};
        f32x4 g2 = {0.f, 0.f, 0.f, 0.f};
        #pragma unroll 2
        for (int s = 0; s < 4; s++) {
            u32x4 av = *(const u32x4*)(smem + F2T + m * 128 + s * 32 + quad * 8);
            u32x4 bv1 = *(const u32x4*)(m1P + (((size_t)(s * 8 + wv) * 64 + lane) << 3));
            u32x4 bv2 = *(const u32x4*)(m1P + (((size_t)(s * 8 + wv + 4) * 64 + lane) << 3));
            g1 = __builtin_amdgcn_mfma_f32_16x16x32_bf16(
                __builtin_bit_cast(bf16x8, av), __builtin_bit_cast(bf16x8, bv1), g1, 0, 0, 0);
            g2 = __builtin_amdgcn_mfma_f32_16x16x32_bf16(
                __builtin_bit_cast(bf16x8, av), __builtin_bit_cast(bf16x8, bv2), g2, 0, 0, 0);
        }
        int o1 = wv * 16 + col, o2 = (wv + 4) * 16 + col;
        float bb1 = m1_b[o1], bb2 = m1_b[o2];
        #pragma unroll
        for (int r = 0; r < 4; r++) {
            int pr = quad * 4 + r;
            smem[H1OFF + pr * 136 + o1] = f2bf(lrelu(g1[r] + bb1));
            smem[H1OFF + pr * 136 + o2] = f2bf(lrelu(g2[r] + bb2));
        }
    }
    __syncthreads();

    // GEMM2: flow_feat = leaky(m2 @ h1 + b2) -> d_out + ff (fp32 LDS)
    {
        float* ffp = (float*)(smem + FFOFF);
        f32x4 g = {0.f, 0.f, 0.f, 0.f};
        #pragma unroll 2
        for (int s = 0; s < 4; s++) {
            u32x4 av = *(const u32x4*)(smem + H1OFF + m * 136 + s * 32 + quad * 8);
            u32x4 bv = *(const u32x4*)(m2P + (((size_t)(s * 4 + wv) * 64 + lane) << 3));
            g = __builtin_amdgcn_mfma_f32_16x16x32_bf16(
                __builtin_bit_cast(bf16x8, av), __builtin_bit_cast(bf16x8, bv), g, 0, 0, 0);
        }
        int o = wv * 16 + col;
        float bb = m2_b[o];
        #pragma unroll
        for (int r = 0; r < 4; r++) {
            int pr = quad * 4 + r;
            float v = lrelu(g[r] + bb);
            dout[((size_t)b * 64 + o) * NPTS + n0 + pr] = v;
            ffp[pr * 68 + o] = v;
        }
    }
    __syncthreads();

    // flow = cl_w @ ff + cl_b  (rolled)
    if (t < 48) {
        float* ffp = (float*)(smem + FFOFF);
        int pp = t & 15, oo = t >> 4;
        float a = cl_b[oo];
        #pragma unroll 8
        for (int i = 0; i < 64; i++)
            a += cl_w[oo * 64 + i] * ffp[pp * 68 + i];
        dout[(size_t)NB * 64 * NPTS + ((size_t)b * 3 + oo) * NPTS + n0 + pp] = a;
    }
}

// ---------------------------------------------------------------------------
extern "C" void kernel_launch(void* const* d_in, const int* in_sizes, int n_in,
                              void* d_out, int out_size, void* d_ws, size_t ws_size,
                              hipStream_t stream) {
    const float* xyz   = (const float*)d_in[0];
    const float* feat  = (const float*)d_in[1];
    const int*   knn   = (const int*)d_in[2];
    const float* wn1_w = (const float*)d_in[3];
    const float* wn1_b = (const float*)d_in[4];
    const float* lin1w = (const float*)d_in[5];
    const float* lin1b = (const float*)d_in[6];
    const float* wn2_w = (const float*)d_in[7];
    const float* wn2_b = (const float*)d_in[8];
    const float* lin2w = (const float*)d_in[9];
    const float* lin2b = (const float*)d_in[10];
    const float* m1_w  = (const float*)d_in[11];
    const float* m1_b  = (const float*)d_in[12];
    const float* m2_w  = (const float*)d_in[13];
    const float* m2_b  = (const float*)d_in[14];
    const float* cl_w  = (const float*)d_in[15];
    const float* cl_b  = (const float*)d_in[16];
    float* out = (float*)d_out;

    char* ws = (char*)d_ws;
    const size_t BN = (size_t)NB * NPTS;
    u16*   fcT1 = (u16*)(ws);                      // BN*136*2 = 8,912,896
    u16*   fcT2 = (u16*)(ws + 8912896);            // 8,912,896
    float* xyzF = (float*)(ws + 17825792);         // 524,288
    u16*   lw1P = (u16*)(ws + 18350080);           // 278,528
    u16*   lw2P = (u16*)(ws + 18628608);           // 278,528
    u16*   m1P  = (u16*)(ws + 18907136);           // 32,768
    u16*   m2P  = (u16*)(ws + 18939904);           // 16,384 -> total 18,956,288

    (void)in_sizes; (void)n_in; (void)out_size; (void)ws_size;

    pack_all<<<dim3(660), dim3(256), 0, stream>>>(
        xyz, feat, fcT1, fcT2, xyzF,
        lin1w, lin2w, m1_w, m2_w, lw1P, lw2P, m1P, m2P);
    pc_kernel0<<<dim3(BN / 16), dim3(256), 0, stream>>>(
        fcT1, xyzF, knn, wn1_w, wn1_b, lw1P, lin1b, fcT2);
    pc_kernel1<<<dim3(BN / 16), dim3(256), 0, stream>>>(
        fcT2, xyzF, knn, wn2_w, wn2_b, lw2P, lin2b,
        m1P, m1_b, m2P, m2_b, cl_w, cl_b, out);
}